// Round 12
// baseline (33.725 us; speedup 1.0000x reference)
//
#include <hip/hip_runtime.h>
#include <hip/hip_bf16.h>

#define CAP 8
#define EPSF 1e-8f
#define NMS_THR 0.7f
#define TOPN 1000
#define ITILE 64                       // i-rows per tile (T=144 blocks @ n=2048)
#define QCAP 8192                      // LDS candidate queue (32KB); avg ~245
#define CAPR 64                        // LDS row-cache slots (64 * 256B = 16KB)
#define SCRATCH_ROWS 512               // global overflow rows (zero-cost if unused)

// ---------------------------------------------------------------------------
// Rotated-rect intersection area (verified absmax==0 R1-R11): faithful fp32
// Sutherland-Hodgman clip, all compile-time indices, zero scratch.
// ---------------------------------------------------------------------------
__device__ __forceinline__ float rect_inter_area_cs(
    float xc1, float yc1, float w1, float h1, float c1, float s1,
    float xc2, float yc2, float w2, float h2, float c2, float s2)
{
    float px[CAP], py[CAP];
    {
        float lx0 = -0.5f * w1, lx1 = 0.5f * w1;
        float ly0 = -0.5f * h1, ly1 = 0.5f * h1;
        px[0] = xc1 + lx0 * c1 - ly0 * s1;  py[0] = yc1 + lx0 * s1 + ly0 * c1;
        px[1] = xc1 + lx1 * c1 - ly0 * s1;  py[1] = yc1 + lx1 * s1 + ly0 * c1;
        px[2] = xc1 + lx1 * c1 - ly1 * s1;  py[2] = yc1 + lx1 * s1 + ly1 * c1;
        px[3] = xc1 + lx0 * c1 - ly1 * s1;  py[3] = yc1 + lx0 * s1 + ly1 * c1;
#pragma unroll
        for (int s2i = 4; s2i < CAP; ++s2i) { px[s2i] = 0.f; py[s2i] = 0.f; }
    }
    float qx[4], qy[4];
    {
        float lx0 = -0.5f * w2, lx1 = 0.5f * w2;
        float ly0 = -0.5f * h2, ly1 = 0.5f * h2;
        qx[0] = xc2 + lx0 * c2 - ly0 * s2;  qy[0] = yc2 + lx0 * s2 + ly0 * c2;
        qx[1] = xc2 + lx1 * c2 - ly0 * s2;  qy[1] = yc2 + lx1 * s2 + ly0 * c2;
        qx[2] = xc2 + lx1 * c2 - ly1 * s2;  qy[2] = yc2 + lx1 * s2 + ly1 * c2;
        qx[3] = xc2 + lx0 * c2 - ly1 * s2;  qy[3] = yc2 + lx0 * s2 + ly1 * c2;
    }

    int n = 4;
#pragma unroll
    for (int e = 0; e < 4; ++e) {
        float p0x = qx[e], p0y = qy[e];
        float ex = qx[(e + 1) & 3] - p0x, ey = qy[(e + 1) & 3] - p0y;

        float pxp = px[0], pyp = py[0];
#pragma unroll
        for (int s = 1; s < CAP; ++s)
            if (s == n - 1) { pxp = px[s]; pyp = py[s]; }
        float dp = ex * (pyp - p0y) - ey * (pxp - p0x);

        float nx_[CAP], ny_[CAP];
#pragma unroll
        for (int s = 0; s < CAP; ++s) { nx_[s] = 0.f; ny_[s] = 0.f; }
        int m = 0;

#pragma unroll
        for (int k = 0; k < CAP; ++k) {
            bool act = (k < n);
            float pxc = px[k], pyc = py[k];
            float dc = ex * (pyc - p0y) - ey * (pxc - p0x);
            bool cin = (dc >= 0.0f), pin = (dp >= 0.0f);

            float den = dp - dc;
            den = (fabsf(den) < EPSF) ? EPSF : den;
            float t = dp / den;
            float ix = pxp + t * (pxc - pxp);
            float iy = pyp + t * (pyc - pyp);

            bool emit_cross = act && (cin != pin);
            if (emit_cross) {
#pragma unroll
                for (int s = 0; s < CAP; ++s)
                    if (s == m) { nx_[s] = ix; ny_[s] = iy; }
                ++m;
            }
            bool emit_cur = act && cin;
            if (emit_cur) {
#pragma unroll
                for (int s = 0; s < CAP; ++s)
                    if (s == m) { nx_[s] = pxc; ny_[s] = pyc; }
                ++m;
            }
            if (act) { pxp = pxc; pyp = pyc; dp = dc; }
        }
        n = (m < CAP) ? m : CAP;
#pragma unroll
        for (int s = 0; s < CAP; ++s) { px[s] = nx_[s]; py[s] = ny_[s]; }
    }

    if (n < 3) return 0.0f;
    float s = 0.0f;
#pragma unroll
    for (int k = 0; k < CAP; ++k) {
        if (k < n) {
            float nxk = px[(k + 1) & (CAP - 1)];
            float nyk = py[(k + 1) & (CAP - 1)];
            if (k == n - 1) { nxk = px[0]; nyk = py[0]; }
            s += px[k] * nyk - py[k] * nxk;
        }
    }
    return 0.5f * fabsf(s);
}

__device__ __forceinline__ unsigned long long rl64(unsigned long long v, int l) {
    unsigned int lo = (unsigned int)__builtin_amdgcn_readlane((int)(unsigned int)v, l);
    unsigned int hi = (unsigned int)__builtin_amdgcn_readlane((int)(v >> 32), l);
    return ((unsigned long long)hi << 32) | lo;
}

// ---------------------------------------------------------------------------
// Kernel 1: tiled pair filter. ITILE=64 -> 144 live blocks (one scheduling
// round). Suppressing pairs stored DIRECTLY into the block's private global
// slice (slice == worst-case tile pairs -> no overflow possible, no global
// counters, no memset node). q overflow (pathological) clips inline.
// ---------------------------------------------------------------------------
__global__ __launch_bounds__(256)
void filter_kernel(const float* __restrict__ boxes,
                   unsigned int* __restrict__ cnt_per_block,
                   unsigned int* __restrict__ pairs, int slice, int n)
{
    __shared__ float4 atile[2 * ITILE];         // 2KB
    __shared__ unsigned int q[QCAP];            // 32KB candidate queue
    __shared__ int qcnt, scnt;

    const int tid = threadIdx.x;
    const int bid = blockIdx.x;

    // decode blockIdx -> (jt, it) over live tiles (verified R9-R11 formula)
    const int itiles = (n + ITILE - 1) / ITILE;
    const int jtiles = (n + 255) / 256;
    int L2 = bid, jt = -1, it = 0;
    for (int q2 = 0; q2 < jtiles; ++q2) {
        int c2 = (q2 * 256 + 254) / ITILE + 1;
        c2 = (c2 < itiles) ? c2 : itiles;
        if (jt < 0) {
            if (L2 < c2) { jt = q2; it = L2; }
            else L2 -= c2;
        }
    }
    const int i0 = it * ITILE;
    const int j = jt * 256 + tid;

    if (tid == 0) { qcnt = 0; scnt = 0; }
    if (tid < ITILE) {                          // inline prep of the i-tile
        int i = i0 + tid;
        if (i < n) {
            const float* b = boxes + (size_t)i * 5;
            float x = b[0], y = b[1], w = b[2], h = b[3], th = b[4];
            atile[2 * tid]     = make_float4(x, y, w, h);
            atile[2 * tid + 1] = make_float4(cosf(th), sinf(th),
                                             0.5f * sqrtf(w * w + h * h), w * h);
        } else {
            atile[2 * tid]     = make_float4(0.f, 0.f, 0.f, 0.f);
            atile[2 * tid + 1] = make_float4(0.f, 0.f, 0.f, 0.f);
        }
    }
    __syncthreads();

    float4 B0, B1;
    bool jok = (j < n);
    if (jok) {
        const float* b = boxes + (size_t)j * 5;
        float x = b[0], y = b[1], w = b[2], h = b[3], th = b[4];
        B0 = make_float4(x, y, w, h);
        B1 = make_float4(cosf(th), sinf(th),
                         0.5f * sqrtf(w * w + h * h), w * h);
    } else { B0 = make_float4(0,0,0,0); B1 = make_float4(0,0,0,0); }

    // cheap-reject sweep (verified math). NOT unrolled: runtime ii indexes
    // LDS atile; keeps the rare inline-clip path to one instantiation.
    for (int ii = 0; ii < ITILE; ++ii) {
        int i = i0 + ii;
        float4 A0 = atile[2 * ii], A1 = atile[2 * ii + 1];
        bool pass = jok && (j > i) && (i < n);
        float dx = A0.x - B0.x, dy = A0.y - B0.y;
        float rr = A1.z + B1.z + 1e-2f;
        pass = pass && (dx * dx + dy * dy <= rr * rr);
        float amin = fminf(A1.w, B1.w), amax = fmaxf(A1.w, B1.w);
        pass = pass && (amin >= 0.699f * amax);
        if (pass) {
            int idx = atomicAdd(&qcnt, 1);
            if (idx < QCAP) {
                q[idx] = ((unsigned int)ii << 16) | (unsigned int)j;
            } else {
                // pathological q overflow: clip inline (divergent but correct)
                float a1 = A1.w, a2 = B1.w;
                float inter = rect_inter_area_cs(
                    A0.x, A0.y, A0.z, A0.w, A1.x, A1.y,
                    B0.x, B0.y, B0.z, B0.w, B1.x, B1.y);
                float iou = inter / (a1 + a2 - inter + EPSF);
                if (iou >= NMS_THR) {
                    int s2 = atomicAdd(&scnt, 1);
                    if (s2 < slice)
                        pairs[(size_t)bid * slice + s2] =
                            ((unsigned int)i << 16) | (unsigned int)j;
                }
            }
        }
    }
    __syncthreads();

    // full-lane clip drain; suppressors -> private global slice directly
    int qn = (qcnt < QCAP) ? qcnt : QCAP;
    for (int t = tid; t < qn; t += 256) {
        unsigned int pk = q[t];
        int ii = (int)(pk >> 16), j2 = (int)(pk & 0xffffu);
        int i2 = i0 + ii;
        float4 A0 = atile[2 * ii], A1 = atile[2 * ii + 1];
        const float* b = boxes + (size_t)j2 * 5;
        float x = b[0], y = b[1], w = b[2], h = b[3], th = b[4];
        float cj = cosf(th), sj = sinf(th);
        float a1 = A1.w, a2 = w * h;
        float inter = rect_inter_area_cs(A0.x, A0.y, A0.z, A0.w, A1.x, A1.y,
                                         x, y, w, h, cj, sj);
        float iou = inter / (a1 + a2 - inter + EPSF);
        if (iou >= NMS_THR) {
            int s2 = atomicAdd(&scnt, 1);
            if (s2 < slice)
                pairs[(size_t)bid * slice + s2] =
                    ((unsigned int)i2 << 16) | (unsigned int)j2;
        }
    }
    __syncthreads();

    if (tid == 0)
        cnt_per_block[bid] = (unsigned int)((scnt < slice) ? scnt : slice);
}

// ---------------------------------------------------------------------------
// Kernel 2: one block, 256 threads (verified R11 body minus ovf machinery).
// Rebuild sparse suppression rows from the pair slices into LDS, then the
// verified wave-0 greedy serial core.
// ---------------------------------------------------------------------------
__global__ __launch_bounds__(256, 1)
void greedy_kernel(const unsigned int* __restrict__ cnt_per_block,
                   const unsigned int* __restrict__ pairs, int slice,
                   unsigned int* __restrict__ scratch32,   // SCRATCH_ROWS*64
                   int* __restrict__ keep, int n, int T)
{
    __shared__ unsigned int rowdat32[CAPR * 64];   // 16KB row cache
    __shared__ unsigned int szv32[64];             // 32 chunks x 2 halves
    __shared__ int bexcl_lds[32];
    __shared__ int Rtot;

    const int tid = threadIdx.x;
    const int chunks = (n + 63) >> 6;

    for (int t = tid; t < 64; t += 256) szv32[t] = 0u;
    __syncthreads();

    // pass 1: summary bits
    for (int b = tid; b < T; b += 256) {
        int cb = (int)cnt_per_block[b];
        if (cb > slice) cb = slice;
        for (int t2 = 0; t2 < cb; ++t2) {
            unsigned int p = pairs[(size_t)b * slice + t2];
            int i = (int)(p >> 16);
            atomicOr(&szv32[((i >> 6) << 1) + ((i >> 5) & 1)], 1u << (i & 31));
        }
    }
    __syncthreads();

    // wave0: prefix-scan nonzero-row counts -> slot bases
    if (tid < 64) {
        int lane = tid;
        unsigned long long szv = (lane < chunks)
            ? ((unsigned long long)szv32[2 * lane] |
               ((unsigned long long)szv32[2 * lane + 1] << 32)) : 0ULL;
        int pc = __popcll(szv);
        int pref = pc;
#pragma unroll
        for (int d = 1; d < 64; d <<= 1) {
            int t = __shfl_up(pref, d);
            if (lane >= d) pref += t;
        }
        if (lane < chunks) bexcl_lds[lane] = pref - pc;
        if (lane == chunks - 1) Rtot = pref;
    }
    __syncthreads();

    int R = Rtot;
    int Rc = (R < CAPR) ? R : CAPR;
    int Rs = ((R < CAPR + SCRATCH_ROWS) ? R : (CAPR + SCRATCH_ROWS)) - Rc;
    for (int t = tid; t < Rc * 64; t += 256) rowdat32[t] = 0u;
    for (int t = tid; t < Rs * 64; t += 256) scratch32[t] = 0u;
    __syncthreads();

    // pass 2: scatter suppression bits into the row cache
    for (int b = tid; b < T; b += 256) {
        int cb = (int)cnt_per_block[b];
        if (cb > slice) cb = slice;
        for (int t2 = 0; t2 < cb; ++t2) {
            unsigned int p = pairs[(size_t)b * slice + t2];
            int i = (int)(p >> 16), jj = (int)(p & 0xffffu);
            int c = i >> 6;
            unsigned long long szc =
                (unsigned long long)szv32[2 * c] |
                ((unsigned long long)szv32[2 * c + 1] << 32);
            int slot = bexcl_lds[c] +
                (int)__popcll(szc & (((i & 63) == 0) ? 0ULL
                                     : ((~0ULL) >> (64 - (i & 63)))));
            if (slot < CAPR)
                atomicOr(&rowdat32[slot * 64 + (jj >> 5)], 1u << (jj & 31));
            else if (slot < CAPR + SCRATCH_ROWS)
                atomicOr(&scratch32[(slot - CAPR) * 64 + (jj >> 5)],
                         1u << (jj & 31));
        }
    }
    __syncthreads();

    // verified serial greedy core (wave 0)
    if (tid >= 64) return;
    {
        const int lane = tid;
        unsigned long long szv = (lane < chunks)
            ? ((unsigned long long)szv32[2 * lane] |
               ((unsigned long long)szv32[2 * lane + 1] << 32)) : 0ULL;
        int base_excl = (lane < chunks) ? bexcl_lds[lane] : 0;

        auto rowread = [&](int slot, int word) -> unsigned long long {
            if (slot < CAPR)
                return (unsigned long long)rowdat32[slot * 64 + 2 * word] |
                       ((unsigned long long)rowdat32[slot * 64 + 2 * word + 1]
                        << 32);
            if (slot < CAPR + SCRATCH_ROWS)
                return (unsigned long long)
                           scratch32[(slot - CAPR) * 64 + 2 * word] |
                       ((unsigned long long)
                           scratch32[(slot - CAPR) * 64 + 2 * word + 1] << 32);
            return 0ULL;   // beyond scratch: pathological only
        };

        unsigned long long acc = 0ULL;
        int cnt = 0;

        for (int c = 0; c < chunks; ++c) {
            if (cnt >= TOPN) break;
            const int base = c << 6;
            unsigned long long cw = rl64(acc, c);
            unsigned long long nzc = rl64(szv, c);
            unsigned long long valid =
                (n - base >= 64) ? ~0ULL : ((1ULL << (n - base)) - 1ULL);
            unsigned long long cand = ~cw & valid;
            int rem = TOPN - cnt;

            unsigned long long kmask;
            if ((nzc & cand) == 0ULL && __popcll(cand) <= rem) {
                kmask = cand;                       // zero-memory fast path
            } else {
                int bexc = __builtin_amdgcn_readlane(base_excl, c);
                unsigned long long D = 0ULL;
                if ((nzc >> lane) & 1ULL) {
                    int slot = bexc +
                        (int)__popcll(nzc & ((lane == 0) ? 0ULL
                                             : ((~0ULL) >> (64 - lane))));
                    D = rowread(slot, c);
                }
                unsigned long long intra = __ballot((D & cand) != 0ULL);
                if ((intra & cand) == 0ULL && __popcll(cand) <= rem) {
                    kmask = cand;                   // parallel decision
                } else {
                    kmask = 0ULL;                   // serial fallback (rare)
                    int cl = cnt;
#pragma unroll
                    for (int k = 0; k < 64; ++k) {
                        if (!((cw >> k) & 1ULL) && cl < TOPN && (base + k) < n) {
                            cw |= rl64(D, k);
                            kmask |= (1ULL << k);
                            ++cl;
                        }
                    }
                }
            }

            if ((kmask >> lane) & 1ULL)
                keep[cnt + __popcll(kmask & ((1ULL << lane) - 1ULL))] =
                    base + lane;
            cnt += __popcll(kmask);

            unsigned long long orrows = kmask & nzc;
            if (orrows) {
                int bexc = __builtin_amdgcn_readlane(base_excl, c);
                while (orrows) {
                    int r = (int)__builtin_ctzll(orrows);
                    orrows &= orrows - 1ULL;
                    int slot = bexc +
                        (int)__popcll(nzc & ((r == 0) ? 0ULL
                                             : ((~0ULL) >> (64 - r))));
                    acc |= rowread(slot, lane & 31);
                }
            }
        }

        for (int t = cnt + lane; t < TOPN; t += 64) keep[t] = -1;
    }
}

extern "C" void kernel_launch(void* const* d_in, const int* in_sizes, int n_in,
                              void* d_out, int out_size, void* d_ws, size_t ws_size,
                              hipStream_t stream) {
    const float* boxes = (const float*)d_in[0];
    int n = in_sizes[0] / 5;                     // 2048
    int* keep = (int*)d_out;

    // live-tile count T (same formula as kernel decode)
    const int itiles = (n + ITILE - 1) / ITILE;
    const int jtiles = (n + 255) / 256;
    int T = 0;
    for (int q2 = 0; q2 < jtiles; ++q2) {
        int c2 = (q2 * 256 + 254) / ITILE + 1;
        T += (c2 < itiles) ? c2 : itiles;
    }

    // ws layout: cnt_per_block(4T) | pairs(T*slice*4) | scratch(SCRATCH_ROWS*256)
    unsigned int* cnt_per_block = (unsigned int*)d_ws;
    size_t off_pairs = (((size_t)T * 4) + 255) & ~(size_t)255;
    size_t fixed_tail = (size_t)SCRATCH_ROWS * 256 + 256;
    long avail = (long)ws_size - (long)off_pairs - (long)fixed_tail;
    int slice = 256 * ITILE;                     // worst-case pairs per tile
    long maxslice = avail / ((long)T * 4);
    if (slice > maxslice) slice = (int)maxslice; // smaller ws: clamped (safe)
    unsigned int* pairs = (unsigned int*)((char*)d_ws + off_pairs);
    unsigned int* scratch32 = pairs + (size_t)T * slice;

    filter_kernel<<<T, 256, 0, stream>>>(boxes, cnt_per_block, pairs, slice, n);
    greedy_kernel<<<1, 256, 0, stream>>>(cnt_per_block, pairs, slice,
                                         scratch32, keep, n, T);
}

// Round 13
// 26.339 us; speedup vs baseline: 1.2804x; 1.2804x over previous
//
#include <hip/hip_runtime.h>
#include <hip/hip_bf16.h>

#define CAP 8
#define EPSF 1e-8f
#define NMS_THR 0.7f
#define TOPN 1000
#define ITILE 16                       // i-rows per tile -> T=576 blocks @ n=2048
#define QCAP (256 * ITILE)             // 4096 = worst-case tile pairs (16KB LDS)
#define PCAP 8192                      // LDS pair list in greedy (32KB)
#define CAPR 64                        // LDS row-cache slots (64 * 256B = 16KB)
#define SCRATCH_ROWS 512               // global overflow rows (zero-cost if unused)

// ---------------------------------------------------------------------------
// Rotated-rect intersection area (verified absmax==0 R1-R12): faithful fp32
// Sutherland-Hodgman clip, all compile-time indices, zero scratch.
// ---------------------------------------------------------------------------
__device__ __forceinline__ float rect_inter_area_cs(
    float xc1, float yc1, float w1, float h1, float c1, float s1,
    float xc2, float yc2, float w2, float h2, float c2, float s2)
{
    float px[CAP], py[CAP];
    {
        float lx0 = -0.5f * w1, lx1 = 0.5f * w1;
        float ly0 = -0.5f * h1, ly1 = 0.5f * h1;
        px[0] = xc1 + lx0 * c1 - ly0 * s1;  py[0] = yc1 + lx0 * s1 + ly0 * c1;
        px[1] = xc1 + lx1 * c1 - ly0 * s1;  py[1] = yc1 + lx1 * s1 + ly0 * c1;
        px[2] = xc1 + lx1 * c1 - ly1 * s1;  py[2] = yc1 + lx1 * s1 + ly1 * c1;
        px[3] = xc1 + lx0 * c1 - ly1 * s1;  py[3] = yc1 + lx0 * s1 + ly1 * c1;
#pragma unroll
        for (int s2i = 4; s2i < CAP; ++s2i) { px[s2i] = 0.f; py[s2i] = 0.f; }
    }
    float qx[4], qy[4];
    {
        float lx0 = -0.5f * w2, lx1 = 0.5f * w2;
        float ly0 = -0.5f * h2, ly1 = 0.5f * h2;
        qx[0] = xc2 + lx0 * c2 - ly0 * s2;  qy[0] = yc2 + lx0 * s2 + ly0 * c2;
        qx[1] = xc2 + lx1 * c2 - ly0 * s2;  qy[1] = yc2 + lx1 * s2 + ly0 * c2;
        qx[2] = xc2 + lx1 * c2 - ly1 * s2;  qy[2] = yc2 + lx1 * s2 + ly1 * c2;
        qx[3] = xc2 + lx0 * c2 - ly1 * s2;  qy[3] = yc2 + lx0 * s2 + ly1 * c2;
    }

    int n = 4;
#pragma unroll
    for (int e = 0; e < 4; ++e) {
        float p0x = qx[e], p0y = qy[e];
        float ex = qx[(e + 1) & 3] - p0x, ey = qy[(e + 1) & 3] - p0y;

        float pxp = px[0], pyp = py[0];
#pragma unroll
        for (int s = 1; s < CAP; ++s)
            if (s == n - 1) { pxp = px[s]; pyp = py[s]; }
        float dp = ex * (pyp - p0y) - ey * (pxp - p0x);

        float nx_[CAP], ny_[CAP];
#pragma unroll
        for (int s = 0; s < CAP; ++s) { nx_[s] = 0.f; ny_[s] = 0.f; }
        int m = 0;

#pragma unroll
        for (int k = 0; k < CAP; ++k) {
            bool act = (k < n);
            float pxc = px[k], pyc = py[k];
            float dc = ex * (pyc - p0y) - ey * (pxc - p0x);
            bool cin = (dc >= 0.0f), pin = (dp >= 0.0f);

            float den = dp - dc;
            den = (fabsf(den) < EPSF) ? EPSF : den;
            float t = dp / den;
            float ix = pxp + t * (pxc - pxp);
            float iy = pyp + t * (pyc - pyp);

            bool emit_cross = act && (cin != pin);
            if (emit_cross) {
#pragma unroll
                for (int s = 0; s < CAP; ++s)
                    if (s == m) { nx_[s] = ix; ny_[s] = iy; }
                ++m;
            }
            bool emit_cur = act && cin;
            if (emit_cur) {
#pragma unroll
                for (int s = 0; s < CAP; ++s)
                    if (s == m) { nx_[s] = pxc; ny_[s] = pyc; }
                ++m;
            }
            if (act) { pxp = pxc; pyp = pyc; dp = dc; }
        }
        n = (m < CAP) ? m : CAP;
#pragma unroll
        for (int s = 0; s < CAP; ++s) { px[s] = nx_[s]; py[s] = ny_[s]; }
    }

    if (n < 3) return 0.0f;
    float s = 0.0f;
#pragma unroll
    for (int k = 0; k < CAP; ++k) {
        if (k < n) {
            float nxk = px[(k + 1) & (CAP - 1)];
            float nyk = py[(k + 1) & (CAP - 1)];
            if (k == n - 1) { nxk = px[0]; nyk = py[0]; }
            s += px[k] * nyk - py[k] * nxk;
        }
    }
    return 0.5f * fabsf(s);
}

__device__ __forceinline__ unsigned long long rl64(unsigned long long v, int l) {
    unsigned int lo = (unsigned int)__builtin_amdgcn_readlane((int)(unsigned int)v, l);
    unsigned int hi = (unsigned int)__builtin_amdgcn_readlane((int)(v >> 32), l);
    return ((unsigned long long)hi << 32) | lo;
}

// ---------------------------------------------------------------------------
// Kernel 1: tiled pair filter. ITILE=16 -> T=576 blocks (good occupancy,
// R8-verified shape), inline trig (R11-verified), unrolled sweep, full-lane
// clip drain. Suppressors stored directly into the block's private global
// slice; slice == QCAP == worst-case tile pairs -> overflow impossible,
// no global counters, no memset node.
// ---------------------------------------------------------------------------
__global__ __launch_bounds__(256)
void filter_kernel(const float* __restrict__ boxes,
                   unsigned int* __restrict__ cnt_per_block,
                   unsigned int* __restrict__ pairs, int slice, int n)
{
    __shared__ float4 atile[2 * ITILE];
    __shared__ unsigned int q[QCAP];            // 16KB candidate queue
    __shared__ int qcnt, scnt;

    const int tid = threadIdx.x;
    const int bid = blockIdx.x;

    // decode blockIdx -> (jt, it) over live tiles (verified R9-R12 formula)
    const int itiles = (n + ITILE - 1) / ITILE;
    const int jtiles = (n + 255) / 256;
    int L2 = bid, jt = -1, it = 0;
    for (int q2 = 0; q2 < jtiles; ++q2) {
        int c2 = (q2 * 256 + 254) / ITILE + 1;
        c2 = (c2 < itiles) ? c2 : itiles;
        if (jt < 0) {
            if (L2 < c2) { jt = q2; it = L2; }
            else L2 -= c2;
        }
    }
    const int i0 = it * ITILE;
    const int j = jt * 256 + tid;

    if (tid == 0) { qcnt = 0; scnt = 0; }
    if (tid < ITILE) {                          // inline prep of the i-tile
        int i = i0 + tid;
        if (i < n) {
            const float* b = boxes + (size_t)i * 5;
            float x = b[0], y = b[1], w = b[2], h = b[3], th = b[4];
            atile[2 * tid]     = make_float4(x, y, w, h);
            atile[2 * tid + 1] = make_float4(cosf(th), sinf(th),
                                             0.5f * sqrtf(w * w + h * h), w * h);
        } else {
            atile[2 * tid]     = make_float4(0.f, 0.f, 0.f, 0.f);
            atile[2 * tid + 1] = make_float4(0.f, 0.f, 0.f, 0.f);
        }
    }
    __syncthreads();

    float4 B0, B1;
    bool jok = (j < n);
    if (jok) {
        const float* b = boxes + (size_t)j * 5;
        float x = b[0], y = b[1], w = b[2], h = b[3], th = b[4];
        B0 = make_float4(x, y, w, h);
        B1 = make_float4(cosf(th), sinf(th),
                         0.5f * sqrtf(w * w + h * h), w * h);
    } else { B0 = make_float4(0,0,0,0); B1 = make_float4(0,0,0,0); }

    // cheap-reject sweep (verified R6-R12 math); q cannot overflow (QCAP =
    // worst-case tile pairs)
#pragma unroll
    for (int ii = 0; ii < ITILE; ++ii) {
        int i = i0 + ii;
        float4 A0 = atile[2 * ii], A1 = atile[2 * ii + 1];
        bool pass = jok && (j > i) && (i < n);
        float dx = A0.x - B0.x, dy = A0.y - B0.y;
        float rr = A1.z + B1.z + 1e-2f;
        pass = pass && (dx * dx + dy * dy <= rr * rr);
        float amin = fminf(A1.w, B1.w), amax = fmaxf(A1.w, B1.w);
        pass = pass && (amin >= 0.699f * amax);
        if (pass) {
            int idx = atomicAdd(&qcnt, 1);
            q[idx] = ((unsigned int)ii << 16) | (unsigned int)j;
        }
    }
    __syncthreads();

    // full-lane clip drain; suppressors -> private global slice directly
    int qn = qcnt;
    for (int t = tid; t < qn; t += 256) {
        unsigned int pk = q[t];
        int ii = (int)(pk >> 16), j2 = (int)(pk & 0xffffu);
        int i2 = i0 + ii;
        float4 A0 = atile[2 * ii], A1 = atile[2 * ii + 1];
        const float* b = boxes + (size_t)j2 * 5;
        float x = b[0], y = b[1], w = b[2], h = b[3], th = b[4];
        float cj = cosf(th), sj = sinf(th);
        float a1 = A1.w, a2 = w * h;
        float inter = rect_inter_area_cs(A0.x, A0.y, A0.z, A0.w, A1.x, A1.y,
                                         x, y, w, h, cj, sj);
        float iou = inter / (a1 + a2 - inter + EPSF);
        if (iou >= NMS_THR) {
            int s2 = atomicAdd(&scnt, 1);
            if (s2 < slice)                      // only if ws-clamped slice
                pairs[(size_t)bid * slice + s2] =
                    ((unsigned int)i2 << 16) | (unsigned int)j2;
        }
    }
    __syncthreads();

    if (tid == 0)
        cnt_per_block[bid] = (unsigned int)((scnt < slice) ? scnt : slice);
}

// ---------------------------------------------------------------------------
// Kernel 2: one block, 256 threads. ONE global walk stages all suppressing
// pairs into LDS plist (latency-hidden, independent loads); summary, scan,
// scatter, and the verified serial core then run from LDS. If plist
// overflows (pathological), fall back to the verified R11/R12 global
// two-pass — duplicates are harmless (atomicOr idempotent).
// ---------------------------------------------------------------------------
__global__ __launch_bounds__(256, 1)
void greedy_kernel(const unsigned int* __restrict__ cnt_per_block,
                   const unsigned int* __restrict__ pairs, int slice,
                   unsigned int* __restrict__ scratch32,   // SCRATCH_ROWS*64
                   int* __restrict__ keep, int n, int T)
{
    __shared__ unsigned int plist[PCAP];           // 32KB staged pair list
    __shared__ unsigned int rowdat32[CAPR * 64];   // 16KB row cache
    __shared__ unsigned int szv32[64];             // 32 chunks x 2 halves
    __shared__ int bexcl_lds[32];
    __shared__ int Rtot, pcnt, ovf;

    const int tid = threadIdx.x;
    const int chunks = (n + 63) >> 6;

    if (tid == 0) { pcnt = 0; ovf = 0; }
    for (int t = tid; t < 64; t += 256) szv32[t] = 0u;
    __syncthreads();

    // stage: one pass over the slices into LDS
    for (int b = tid; b < T; b += 256) {
        int cb = (int)cnt_per_block[b];
        if (cb > slice) cb = slice;
        for (int t2 = 0; t2 < cb; ++t2) {
            unsigned int p = pairs[(size_t)b * slice + t2];
            int idx = atomicAdd(&pcnt, 1);
            if (idx < PCAP) plist[idx] = p;
            else ovf = 1;
        }
    }
    __syncthreads();
    int np = (pcnt < PCAP) ? pcnt : PCAP;

    // pass 1: summary bits (from LDS; global re-walk only on overflow)
    for (int t = tid; t < np; t += 256) {
        int i = (int)(plist[t] >> 16);
        atomicOr(&szv32[((i >> 6) << 1) + ((i >> 5) & 1)], 1u << (i & 31));
    }
    if (ovf) {
        for (int b = tid; b < T; b += 256) {
            int cb = (int)cnt_per_block[b];
            if (cb > slice) cb = slice;
            for (int t2 = 0; t2 < cb; ++t2) {
                unsigned int p = pairs[(size_t)b * slice + t2];
                int i = (int)(p >> 16);
                atomicOr(&szv32[((i >> 6) << 1) + ((i >> 5) & 1)],
                         1u << (i & 31));
            }
        }
    }
    __syncthreads();

    // wave0: prefix-scan nonzero-row counts -> slot bases
    if (tid < 64) {
        int lane = tid;
        unsigned long long szv = (lane < chunks)
            ? ((unsigned long long)szv32[2 * lane] |
               ((unsigned long long)szv32[2 * lane + 1] << 32)) : 0ULL;
        int pc = __popcll(szv);
        int pref = pc;
#pragma unroll
        for (int d = 1; d < 64; d <<= 1) {
            int t = __shfl_up(pref, d);
            if (lane >= d) pref += t;
        }
        if (lane < chunks) bexcl_lds[lane] = pref - pc;
        if (lane == chunks - 1) Rtot = pref;
    }
    __syncthreads();

    int R = Rtot;
    int Rc = (R < CAPR) ? R : CAPR;
    int Rs = ((R < CAPR + SCRATCH_ROWS) ? R : (CAPR + SCRATCH_ROWS)) - Rc;
    for (int t = tid; t < Rc * 64; t += 256) rowdat32[t] = 0u;
    for (int t = tid; t < Rs * 64; t += 256) scratch32[t] = 0u;
    __syncthreads();

    // pass 2: scatter suppression bits into the row cache
    auto scatter = [&](unsigned int p) {
        int i = (int)(p >> 16), jj = (int)(p & 0xffffu);
        int c = i >> 6;
        unsigned long long szc =
            (unsigned long long)szv32[2 * c] |
            ((unsigned long long)szv32[2 * c + 1] << 32);
        int slot = bexcl_lds[c] +
            (int)__popcll(szc & (((i & 63) == 0) ? 0ULL
                                 : ((~0ULL) >> (64 - (i & 63)))));
        if (slot < CAPR)
            atomicOr(&rowdat32[slot * 64 + (jj >> 5)], 1u << (jj & 31));
        else if (slot < CAPR + SCRATCH_ROWS)
            atomicOr(&scratch32[(slot - CAPR) * 64 + (jj >> 5)],
                     1u << (jj & 31));
    };
    for (int t = tid; t < np; t += 256) scatter(plist[t]);
    if (ovf) {
        for (int b = tid; b < T; b += 256) {
            int cb = (int)cnt_per_block[b];
            if (cb > slice) cb = slice;
            for (int t2 = 0; t2 < cb; ++t2)
                scatter(pairs[(size_t)b * slice + t2]);
        }
    }
    __syncthreads();

    // verified serial greedy core (wave 0)
    if (tid >= 64) return;
    {
        const int lane = tid;
        unsigned long long szv = (lane < chunks)
            ? ((unsigned long long)szv32[2 * lane] |
               ((unsigned long long)szv32[2 * lane + 1] << 32)) : 0ULL;
        int base_excl = (lane < chunks) ? bexcl_lds[lane] : 0;

        auto rowread = [&](int slot, int word) -> unsigned long long {
            if (slot < CAPR)
                return (unsigned long long)rowdat32[slot * 64 + 2 * word] |
                       ((unsigned long long)rowdat32[slot * 64 + 2 * word + 1]
                        << 32);
            if (slot < CAPR + SCRATCH_ROWS)
                return (unsigned long long)
                           scratch32[(slot - CAPR) * 64 + 2 * word] |
                       ((unsigned long long)
                           scratch32[(slot - CAPR) * 64 + 2 * word + 1] << 32);
            return 0ULL;   // beyond scratch: pathological only
        };

        unsigned long long acc = 0ULL;
        int cnt = 0;

        for (int c = 0; c < chunks; ++c) {
            if (cnt >= TOPN) break;
            const int base = c << 6;
            unsigned long long cw = rl64(acc, c);
            unsigned long long nzc = rl64(szv, c);
            unsigned long long valid =
                (n - base >= 64) ? ~0ULL : ((1ULL << (n - base)) - 1ULL);
            unsigned long long cand = ~cw & valid;
            int rem = TOPN - cnt;

            unsigned long long kmask;
            if ((nzc & cand) == 0ULL && __popcll(cand) <= rem) {
                kmask = cand;                       // zero-memory fast path
            } else {
                int bexc = __builtin_amdgcn_readlane(base_excl, c);
                unsigned long long D = 0ULL;
                if ((nzc >> lane) & 1ULL) {
                    int slot = bexc +
                        (int)__popcll(nzc & ((lane == 0) ? 0ULL
                                             : ((~0ULL) >> (64 - lane))));
                    D = rowread(slot, c);
                }
                unsigned long long intra = __ballot((D & cand) != 0ULL);
                if ((intra & cand) == 0ULL && __popcll(cand) <= rem) {
                    kmask = cand;                   // parallel decision
                } else {
                    kmask = 0ULL;                   // serial fallback (rare)
                    int cl = cnt;
#pragma unroll
                    for (int k = 0; k < 64; ++k) {
                        if (!((cw >> k) & 1ULL) && cl < TOPN && (base + k) < n) {
                            cw |= rl64(D, k);
                            kmask |= (1ULL << k);
                            ++cl;
                        }
                    }
                }
            }

            if ((kmask >> lane) & 1ULL)
                keep[cnt + __popcll(kmask & ((1ULL << lane) - 1ULL))] =
                    base + lane;
            cnt += __popcll(kmask);

            unsigned long long orrows = kmask & nzc;
            if (orrows) {
                int bexc = __builtin_amdgcn_readlane(base_excl, c);
                while (orrows) {
                    int r = (int)__builtin_ctzll(orrows);
                    orrows &= orrows - 1ULL;
                    int slot = bexc +
                        (int)__popcll(nzc & ((r == 0) ? 0ULL
                                             : ((~0ULL) >> (64 - r))));
                    acc |= rowread(slot, lane & 31);
                }
            }
        }

        for (int t = cnt + lane; t < TOPN; t += 64) keep[t] = -1;
    }
}

extern "C" void kernel_launch(void* const* d_in, const int* in_sizes, int n_in,
                              void* d_out, int out_size, void* d_ws, size_t ws_size,
                              hipStream_t stream) {
    const float* boxes = (const float*)d_in[0];
    int n = in_sizes[0] / 5;                     // 2048
    int* keep = (int*)d_out;

    // live-tile count T (same formula as kernel decode)
    const int itiles = (n + ITILE - 1) / ITILE;
    const int jtiles = (n + 255) / 256;
    int T = 0;
    for (int q2 = 0; q2 < jtiles; ++q2) {
        int c2 = (q2 * 256 + 254) / ITILE + 1;
        T += (c2 < itiles) ? c2 : itiles;
    }

    // ws layout: cnt_per_block(4T) | pairs(T*slice*4) | scratch(SCRATCH_ROWS*256)
    unsigned int* cnt_per_block = (unsigned int*)d_ws;
    size_t off_pairs = (((size_t)T * 4) + 255) & ~(size_t)255;
    size_t fixed_tail = (size_t)SCRATCH_ROWS * 256 + 256;
    long avail = (long)ws_size - (long)off_pairs - (long)fixed_tail;
    int slice = QCAP;                            // worst-case pairs per tile
    long maxslice = avail / ((long)T * 4);
    if (slice > maxslice) slice = (int)maxslice; // smaller ws: clamped (safe)
    unsigned int* pairs = (unsigned int*)((char*)d_ws + off_pairs);
    unsigned int* scratch32 = pairs + (size_t)T * slice;

    filter_kernel<<<T, 256, 0, stream>>>(boxes, cnt_per_block, pairs, slice, n);
    greedy_kernel<<<1, 256, 0, stream>>>(cnt_per_block, pairs, slice,
                                         scratch32, keep, n, T);
}